// Round 19
// baseline (199.469 us; speedup 1.0000x reference)
//
#include <hip/hip_runtime.h>
#include <hip/hip_bf16.h>
#include <math.h>

#define BATCH 16
#define LSEQ 4096
#define DMODEL 256
#define NST 16
#define LC 64                   // rows per fused block / scan chunk
#define NCHB (LSEQ / LC)        // 64 chunks per batch
#define MROWS (BATCH * LSEQ)    // 65536
#define LOG2E 1.44269504088896340736f
#define LN2 0.6931471805599453f

typedef float f32x4 __attribute__((ext_vector_type(4)));
typedef float f32x2 __attribute__((ext_vector_type(2)));
typedef short bf16x8 __attribute__((ext_vector_type(8)));

__device__ __forceinline__ float silu_fast(float v) {
  return v * __builtin_amdgcn_rcpf(1.f + __builtin_amdgcn_exp2f(-v * LOG2E));
}
__device__ __forceinline__ float softplus_fast(float v) {
  float l = LN2 * __builtin_amdgcn_logf(1.f + __builtin_amdgcn_exp2f(v * LOG2E));
  return v > 16.f ? v : l;
}
__device__ __forceinline__ uint bf16rne(float f) {
  uint u = __float_as_uint(f);
  return (u + 0x7fffu + ((u >> 16) & 1u)) >> 16;
}
__device__ __forceinline__ float bf2f(ushort u) {
  return __uint_as_float((uint)u << 16);
}
__device__ __forceinline__ ushort f2h(float v) {
  _Float16 h = (_Float16)v;
  return __builtin_bit_cast(ushort, h);
}
__device__ __forceinline__ float h2f(ushort u) {
  return (float)__builtin_bit_cast(_Float16, u);
}
__device__ __forceinline__ uint pk2(float x, float y) {
  return bf16rne(x) | (bf16rne(y) << 16);
}
__device__ __forceinline__ uint4 pk8(float4 a, float4 b) {
  uint4 r;
  r.x = pk2(a.x, a.y);
  r.y = pk2(a.z, a.w);
  r.z = pk2(b.x, b.y);
  r.w = pk2(b.z, b.w);
  return r;
}
// unpack 8 bf16 (uint4) -> 8 floats
__device__ __forceinline__ void ub8(uint4 v, float* o) {
  o[0] = bf2f((ushort)(v.x & 0xffff));
  o[1] = bf2f((ushort)(v.x >> 16));
  o[2] = bf2f((ushort)(v.y & 0xffff));
  o[3] = bf2f((ushort)(v.y >> 16));
  o[4] = bf2f((ushort)(v.z & 0xffff));
  o[5] = bf2f((ushort)(v.z >> 16));
  o[6] = bf2f((ushort)(v.w & 0xffff));
  o[7] = bf2f((ushort)(v.w >> 16));
}

// packed powers: p01={e1,e2} .. p67={e7,e8}, scaled by (s ? e8 : 1).
// Bit-identical pairings to the scalar tree.
__device__ __forceinline__ void pow8pk(float e1, int s, f32x2* p) {
  float e2 = e1 * e1;
  p[0] = f32x2{e1, e2};
  f32x2 e2v = {e2, e2};
  p[1] = p[0] * e2v;                 // {e3, e4}
  f32x2 e4v = {p[1].y, p[1].y};
  p[2] = p[0] * e4v;                 // {e5, e6}
  p[3] = p[1] * e4v;                 // {e7, e8}
  float sel = s ? p[3].y : 1.0f;
  f32x2 selv = {sel, sel};
  p[0] *= selv;
  p[1] *= selv;
  p[2] *= selv;
  p[3] *= selv;
}

// async global(bf16)->LDS, 16 B per lane
__device__ __forceinline__ void glds16(const ushort* g, char* l) {
  __builtin_amdgcn_global_load_lds(
      (const __attribute__((address_space(1))) void*)g,
      (__attribute__((address_space(3))) void*)l, 16, 0, 0);
}

// stage a 256x32 bf16 B k-slice (swizzled layout r*64 + slot*16,
// slot = chunk ^ ((r+(r>>2))&3)); 512 thr: wave w covers 1KB blocks 2w,2w+1.
__device__ __forceinline__ void stageB512(const ushort* gbase, char* dst,
                                          int k0, int lane, int wid) {
#pragma unroll
  for (int c = 0; c < 2; ++c) {
    int r = (wid * 2 + c) * 16 + (lane >> 2);
    int sA = (r + (r >> 2)) & 3;
    int cA = (lane & 3) ^ sA;
    glds16(gbase + (size_t)r * 256 + cA * 8 + k0, dst + (wid * 2 + c) * 1024);
  }
}

// ---------------------------------------------------------------------------
// Weight fp32->bf16 convert (layout unchanged).
// ---------------------------------------------------------------------------
__global__ __launch_bounds__(256) void cvt_weights(
    const float* __restrict__ Win, const float* __restrict__ Wd,
    const float* __restrict__ Wo, const float* __restrict__ WB,
    const float* __restrict__ WC, ushort* __restrict__ dst) {
  size_t i = ((size_t)blockIdx.x * 256 + threadIdx.x) * 8;
  if (i >= 270336) return;
  const float* s;
  size_t o;
  if (i < 131072)      { s = Win; o = i; }
  else if (i < 196608) { s = Wd;  o = i - 131072; }
  else if (i < 262144) { s = Wo;  o = i - 196608; }
  else if (i < 266240) { s = WB;  o = i - 262144; }
  else                 { s = WC;  o = i - 266240; }
  float4 a = *(const float4*)(s + o);
  float4 b = *(const float4*)(s + o + 4);
  *(uint4*)(dst + i) = pk8(a, b);
}

// ---------------------------------------------------------------------------
// gemm_in: xz = x @ W_in^T + b_in. Tile 64x256, grid (2, M/64);
// col<256 -> x_in bf16, col>=256 -> silu(z) bf16.
// ---------------------------------------------------------------------------
__global__ __launch_bounds__(256, 4) void gemm_in(
    const float* __restrict__ A, const ushort* __restrict__ Bbf,
    const float* __restrict__ bias, ushort* __restrict__ out0,
    ushort* __restrict__ out1) {
  constexpr int KD = 256;
  __shared__ char smem[40960];
  const int tid = threadIdx.x;
  const int lane = tid & 63, wid = tid >> 6;
  const int M0 = blockIdx.y * 64;
  const int N0 = blockIdx.x * 256;

  const int rA = tid >> 2, cA = tid & 3;
  const int sA = (rA + (rA >> 2)) & 3;
  const int ldsAoff = rA * 64 + ((cA ^ sA) * 16);
  const float* gA32 = A + (size_t)(M0 + rA) * KD + cA * 8;
  const ushort* gB = Bbf + (size_t)(N0 + rA) * KD + ((cA ^ sA) * 8);

  f32x4 acc[4][4];
#pragma unroll
  for (int i = 0; i < 4; ++i)
#pragma unroll
    for (int j = 0; j < 4; ++j) acc[i][j] = {0.f, 0.f, 0.f, 0.f};

  {
#pragma unroll
    for (int i = 0; i < 4; ++i)
      glds16(gB + (size_t)i * 64 * KD, smem + 4096 + i * 4096 + wid * 1024);
    float4 a0 = *(const float4*)(gA32);
    float4 a1 = *(const float4*)(gA32 + 4);
    *(uint4*)(smem + ldsAoff) = pk8(a0, a1);
  }
  __syncthreads();

  for (int step = 0; step < 8; ++step) {
    const int cur = step & 1;
    char* bufc = smem + cur * 20480;
    char* bufn = smem + (cur ^ 1) * 20480;
    float4 na0, na1;
    if (step < 7) {
      const int k0 = (step + 1) * 32;
#pragma unroll
      for (int i = 0; i < 4; ++i)
        glds16(gB + (size_t)i * 64 * KD + k0,
               bufn + 4096 + i * 4096 + wid * 1024);
      na0 = *(const float4*)(gA32 + k0);
      na1 = *(const float4*)(gA32 + k0 + 4);
    }
    bf16x8 af[4], bfr[4];
#pragma unroll
    for (int i = 0; i < 4; ++i) {
      int r = i * 16 + (lane & 15);
      int slot = (lane >> 4) ^ ((r + (r >> 2)) & 3);
      af[i] = *(const bf16x8*)(bufc + r * 64 + slot * 16);
    }
#pragma unroll
    for (int j = 0; j < 4; ++j) {
      int r = wid * 64 + j * 16 + (lane & 15);
      int slot = (lane >> 4) ^ ((r + (r >> 2)) & 3);
      bfr[j] = *(const bf16x8*)(bufc + 4096 + r * 64 + slot * 16);
    }
#pragma unroll
    for (int i = 0; i < 4; ++i)
#pragma unroll
      for (int j = 0; j < 4; ++j)
        acc[i][j] = __builtin_amdgcn_mfma_f32_16x16x32_bf16(af[i], bfr[j],
                                                            acc[i][j], 0, 0, 0);
    if (step < 7) *(uint4*)(bufn + ldsAoff) = pk8(na0, na1);
    __syncthreads();
  }

  const int rbase = (lane >> 4) * 4;
  const int cn = lane & 15;
#pragma unroll
  for (int i = 0; i < 4; ++i) {
#pragma unroll
    for (int j = 0; j < 4; ++j) {
      int col = N0 + wid * 64 + j * 16 + cn;
      float bs = bias[col];
#pragma unroll
      for (int r = 0; r < 4; ++r) {
        int row = M0 + i * 16 + rbase + r;
        float v = acc[i][j][r] + bs;
        if (col < DMODEL)
          out0[(size_t)row * DMODEL + col] = (ushort)bf16rne(v);
        else
          out1[(size_t)row * DMODEL + (col - DMODEL)] =
              (ushort)bf16rne(silu_fast(v));
      }
    }
  }
}

// ---------------------------------------------------------------------------
// K2 fused_mid (512 thr, 72 KB LDS): conv+silu -> xc tile, delta GEMM
// (single-buffered W_delta), BC GEMM (interleaved), scan pass1 n-split
// packed f32. Emits interleaved dug[row][d] = (dt fp16 | u bf16 << 16)
// instead of separate dl / xc globals.
// ---------------------------------------------------------------------------
__global__ __launch_bounds__(512, 4) void fused_mid(
    const ushort* __restrict__ xin, const ushort* __restrict__ wdl,
    const ushort* __restrict__ wbc, const float* __restrict__ b_delta,
    const float* __restrict__ A_log, const float* __restrict__ conv_w,
    const float* __restrict__ conv_b, uint* __restrict__ dug,
    ushort* __restrict__ bc_g, float* __restrict__ hout,
    float* __restrict__ cumA) {
  __shared__ char smem[73728];
  const int tid = threadIdx.x, lane = tid & 63, wid = tid >> 6;
  const int b = blockIdx.x / NCHB, c = blockIdx.x % NCHB;
  const int l0 = c * LC;
  const size_t row0 = (size_t)b * LSEQ + l0;

  // ---- WBC staging -> @49152
  {
#pragma unroll
    for (int cc = 0; cc < 2; ++cc) {
      int row = (wid * 2 + cc) * 2 + (lane >> 5);
      int cB = (lane & 31) ^ (row & 7);
      glds16(wbc + (size_t)row * 256 + cB * 8,
             smem + 49152 + (wid * 2 + cc) * 1024);
    }
  }
  // ---- W_delta k-step 0 -> @32768
  stageB512(wdl, smem + 32768, 0, lane, wid);

  // ---- conv + silu -> xc tile (LDS only; global emit happens via dug)
  {
    const int dq = tid & 31;
    const int d0 = dq * 8;
    float w0[8], w1[8], w2[8], cb[8];
#pragma unroll
    for (int k = 0; k < 8; ++k) {
      w0[k] = conv_w[(d0 + k) * 3 + 0];
      w1[k] = conv_w[(d0 + k) * 3 + 1];
      w2[k] = conv_w[(d0 + k) * 3 + 2];
      cb[k] = conv_b[d0 + k];
    }
#pragma unroll
    for (int it = 0; it < 4; ++it) {
      const int lr = it * 16 + (tid >> 5);
      const int l = l0 + lr;
      const size_t bp = (row0 + lr) * DMODEL + d0;
      uint4 zf4 = {0u, 0u, 0u, 0u};
      uint4 um = (l > 0) ? *(const uint4*)(xin + bp - DMODEL) : zf4;
      uint4 uc4 = *(const uint4*)(xin + bp);
      uint4 up = (l < LSEQ - 1) ? *(const uint4*)(xin + bp + DMODEL) : zf4;
      float mv[8], cv[8], pv[8], ov[8];
      ub8(um, mv);
      ub8(uc4, cv);
      ub8(up, pv);
#pragma unroll
      for (int k = 0; k < 8; ++k) {
        float o = fmaf(w0[k], mv[k], fmaf(w1[k], cv[k], fmaf(w2[k], pv[k], cb[k])));
        ov[k] = silu_fast(o);
      }
      uint4 r4;
      r4.x = pk2(ov[0], ov[1]);
      r4.y = pk2(ov[2], ov[3]);
      r4.z = pk2(ov[4], ov[5]);
      r4.w = pk2(ov[6], ov[7]);
      *(uint4*)(smem + lr * 512 + ((dq ^ (lr & 7)) * 16)) = r4;
    }
  }
  __syncthreads();  // xc tile + WBC + B-k0 ready

  // ---- delta GEMM (single-buf B) with BC GEMM interleaved
  f32x4 acc[4][2];
#pragma unroll
  for (int i = 0; i < 4; ++i)
#pragma unroll
    for (int j = 0; j < 2; ++j) acc[i][j] = {0.f, 0.f, 0.f, 0.f};
  f32x4 accbc = {0.f, 0.f, 0.f, 0.f};

  for (int step = 0; step < 8; ++step) {
    bf16x8 af[4], bfr[2];
#pragma unroll
    for (int i = 0; i < 4; ++i) {
      int r = i * 16 + (lane & 15);
      int sc = step * 4 + (lane >> 4);
      af[i] = *(const bf16x8*)(smem + r * 512 + ((sc ^ (r & 7)) * 16));
    }
#pragma unroll
    for (int j = 0; j < 2; ++j) {
      int r = wid * 32 + j * 16 + (lane & 15);
      int slot = (lane >> 4) ^ ((r + (r >> 2)) & 3);
      bfr[j] = *(const bf16x8*)(smem + 32768 + r * 64 + slot * 16);
    }
#pragma unroll
    for (int i = 0; i < 4; ++i)
#pragma unroll
      for (int j = 0; j < 2; ++j)
        acc[i][j] = __builtin_amdgcn_mfma_f32_16x16x32_bf16(af[i], bfr[j],
                                                            acc[i][j], 0, 0, 0);
    __syncthreads();  // all reads of B buffer done
    if (step < 7) stageB512(wdl, smem + 32768, (step + 1) * 32, lane, wid);
    {  // BC GEMM step
      int sc = step * 4 + (lane >> 4);
      int ra = (wid >> 1) * 16 + (lane & 15);
      bf16x8 a2 = *(const bf16x8*)(smem + ra * 512 + ((sc ^ (ra & 7)) * 16));
      int br = (wid & 1) * 16 + (lane & 15);
      bf16x8 b2 =
          *(const bf16x8*)(smem + 49152 + br * 512 + ((sc ^ (br & 7)) * 16));
      accbc = __builtin_amdgcn_mfma_f32_16x16x32_bf16(a2, b2, accbc, 0, 0, 0);
    }
    __syncthreads();  // staged B visible
  }

  // ---- delta epilogue -> fp16 tile @32768, swz
  const int rbase = (lane >> 4) * 4;
  const int cn = lane & 15;
#pragma unroll
  for (int i = 0; i < 4; ++i)
#pragma unroll
    for (int j = 0; j < 2; ++j) {
      int col = wid * 32 + j * 16 + cn;
      float bs = b_delta[col];
#pragma unroll
      for (int r = 0; r < 4; ++r) {
        int row = i * 16 + rbase + r;
        *(ushort*)(smem + 32768 + row * 512 +
                   ((col * 2) ^ (((row >> 2) & 3) << 5))) =
            f2h(softplus_fast(acc[i][j][r] + bs));
      }
    }
  // ---- BC epilogue
  {
#pragma unroll
    for (int r = 0; r < 4; ++r) {
      int row = (wid >> 1) * 16 + rbase + r;
      int col = (wid & 1) * 16 + cn;
      ushort bv = (ushort)bf16rne(accbc[r]);
      ((float*)(smem + 65536))[row * 32 + col] = bf2f(bv);
      bc_g[(row0 + row) * 32 + col] = bv;
    }
  }
  __syncthreads();

  // ---- dug coalesced write: (dt fp16 | u bf16 << 16) per (row, d)
#pragma unroll
  for (int it = 0; it < 8; ++it) {
    int idx = it * 512 + tid;          // 0..4095, 4 d per thread
    int row = idx >> 6, d0 = (idx & 63) * 4;
    uint2 dtp = *(const uint2*)(smem + 32768 + row * 512 +
                                ((d0 * 2) ^ (((row >> 2) & 3) << 5)));
    uint2 up = *(const uint2*)(smem + row * 512 +
                               (((d0 >> 3) ^ (row & 7)) * 16) + (d0 & 7) * 2);
    uint4 o;
    o.x = (dtp.x & 0xffffu) | (up.x << 16);
    o.y = (dtp.x >> 16) | (up.x & 0xffff0000u);
    o.z = (dtp.y & 0xffffu) | (up.y << 16);
    o.w = (dtp.y >> 16) | (up.y & 0xffff0000u);
    *(uint4*)(dug + (row0 + row) * DMODEL + d0) = o;
  }

  // ---- scan pass1, n-split, packed f32
  const int d = tid >> 1;
  const int s = tid & 1;
  float Aa2h[8];
  {
    float4 v0 = *(const float4*)(A_log + d * NST + 8 * s);
    float4 v1 = *(const float4*)(A_log + d * NST + 8 * s + 4);
    Aa2h[0] = -LOG2E * __expf(v0.x);
    Aa2h[1] = -LOG2E * __expf(v0.y);
    Aa2h[2] = -LOG2E * __expf(v0.z);
    Aa2h[3] = -LOG2E * __expf(v0.w);
    Aa2h[4] = -LOG2E * __expf(v1.x);
    Aa2h[5] = -LOG2E * __expf(v1.y);
    Aa2h[6] = -LOG2E * __expf(v1.z);
    Aa2h[7] = -LOG2E * __expf(v1.w);
  }
  const float Aa2_0 = -LOG2E * __expf(A_log[d * NST]);
  bool pm = true;
#pragma unroll
  for (int k = 0; k < 8; ++k)
    pm = pm && (fabsf(Aa2h[k] - (float)(8 * s + k + 1) * Aa2_0) <=
                1e-3f * fabsf(Aa2h[k]));

  float sdt = 0.f;
  const int uoff0 = (d & 7) * 2;
  const int uchunk = d >> 3;
  if (pm) {
    f32x2 h2[4];
#pragma unroll
    for (int q = 0; q < 4; ++q) h2[q] = f32x2{0.f, 0.f};
#pragma unroll 4
    for (int l = 0; l < LC; ++l) {
      float dt = h2f(*(const ushort*)(smem + 32768 + l * 512 +
                                      ((d * 2) ^ (((l >> 2) & 3) << 5))));
      float u = bf2f(*(const ushort*)(smem + l * 512 +
                                      ((uchunk ^ (l & 7)) * 16) + uoff0));
      sdt += dt;
      float dtu = dt * u;
      f32x2 dtu2 = {dtu, dtu};
      const float* Bp = (const float*)(smem + 65536) + l * 32 + 8 * s;
      f32x4 B0 = *(const f32x4*)(Bp);
      f32x4 B1 = *(const f32x4*)(Bp + 4);
      f32x2 p[4];
      pow8pk(__builtin_amdgcn_exp2f(dt * Aa2_0), s, p);
      h2[0] = p[0] * h2[0] + dtu2 * B0.xy;
      h2[1] = p[1] * h2[1] + dtu2 * B0.zw;
      h2[2] = p[2] * h2[2] + dtu2 * B1.xy;
      h2[3] = p[3] * h2[3] + dtu2 * B1.zw;
    }
    f32x2 cum[4];
    pow8pk(__builtin_amdgcn_exp2f(sdt * Aa2_0), s, cum);
    const size_t ob =
        (((size_t)(b * NCHB + c)) * DMODEL + d) * NST + 8 * s;
    float4 hv0 = {h2[0].x, h2[0].y, h2[1].x, h2[1].y};
    float4 hv1 = {h2[2].x, h2[2].y, h2[3].x, h2[3].y};
    *(float4*)(hout + ob) = hv0;
    *(float4*)(hout + ob + 4) = hv1;
    float4 cv0 = {cum[0].x, cum[0].y, cum[1].x, cum[1].y};
    float4 cv1 = {cum[2].x, cum[2].y, cum[3].x, cum[3].y};
    *(float4*)(cumA + ob) = cv0;
    *(float4*)(cumA + ob + 4) = cv1;
  } else {
    float h[8];
#pragma unroll
    for (int k = 0; k < 8; ++k) h[k] = 0.f;
#pragma unroll 4
    for (int l = 0; l < LC; ++l) {
      float dt = h2f(*(const ushort*)(smem + 32768 + l * 512 +
                                      ((d * 2) ^ (((l >> 2) & 3) << 5))));
      float u = bf2f(*(const ushort*)(smem + l * 512 +
                                      ((uchunk ^ (l & 7)) * 16) + uoff0));
      sdt += dt;
      float dtu = dt * u;
      const float* Bp = (const float*)(smem + 65536) + l * 32 + 8 * s;
      f32x4 B0 = *(const f32x4*)(Bp);
      f32x4 B1 = *(const f32x4*)(Bp + 4);
      float Bv[8] = {B0.x, B0.y, B0.z, B0.w, B1.x, B1.y, B1.z, B1.w};
#pragma unroll
      for (int k = 0; k < 8; ++k) {
        float ab = __builtin_amdgcn_exp2f(dt * Aa2h[k]);
        h[k] = fmaf(ab, h[k], dtu * Bv[k]);
      }
    }
    const size_t ob =
        (((size_t)(b * NCHB + c)) * DMODEL + d) * NST + 8 * s;
#pragma unroll
    for (int q = 0; q < 2; ++q) {
      float4 hv = {h[q * 4 + 0], h[q * 4 + 1], h[q * 4 + 2], h[q * 4 + 3]};
      *(float4*)(hout + ob + q * 4) = hv;
      float4 cvv = {__builtin_amdgcn_exp2f(sdt * Aa2h[q * 4 + 0]),
                    __builtin_amdgcn_exp2f(sdt * Aa2h[q * 4 + 1]),
                    __builtin_amdgcn_exp2f(sdt * Aa2h[q * 4 + 2]),
                    __builtin_amdgcn_exp2f(sdt * Aa2h[q * 4 + 3])};
      *(float4*)(cumA + ob + q * 4) = cvv;
    }
  }
}

// ---------------------------------------------------------------------------
// Scan combine over 64 chunks; in-place h_out -> h_in.
// ---------------------------------------------------------------------------
__global__ __launch_bounds__(256) void scan_combine(
    float* __restrict__ hstate, const float* __restrict__ cumA) {
  const int t = blockIdx.x * 256 + threadIdx.x;
  const int n = t & (NST - 1);
  const int dd = (t / NST) & (DMODEL - 1);
  const int b = t / (NST * DMODEL);
  float h = 0.f;
  for (int c = 0; c < NCHB; ++c) {
    size_t idx = (((size_t)(b * NCHB + c)) * DMODEL + dd) * NST + n;
    float ho = hstate[idx];
    float ca = cumA[idx];
    hstate[idx] = h;
    h = fmaf(ca, h, ho);
  }
}

// ---------------------------------------------------------------------------
// K3 fused_out (512 thr, 72 KB LDS): scan pass3 (n-split x2, packed f32;
// single interleaved dug stream; s=0 lane owns z + yp + LDS write)
// -> y_pre tile -> GEMM W_out (dbuf) -> d_out.
// ---------------------------------------------------------------------------
__global__ __launch_bounds__(512, 4) void fused_out(
    const uint* __restrict__ dug, const ushort* __restrict__ szy,
    const ushort* __restrict__ bcb, const float* __restrict__ A_log,
    const float* __restrict__ hin, const float* __restrict__ Dskip,
    const ushort* __restrict__ wout, const float* __restrict__ b_out,
    float* __restrict__ out) {
  __shared__ char smem[73728];
  const int tid = threadIdx.x, lane = tid & 63, wid = tid >> 6;
  const int b = blockIdx.x / NCHB, c = blockIdx.x % NCHB;
  const int l0 = c * LC;
  const size_t row0 = (size_t)b * LSEQ + l0;

  // stage BC f32 tile
  {
    int r = tid >> 3, q = tid & 7;
    uint2 v = *(const uint2*)(bcb + (row0 + r) * 32 + q * 4);
    float* dp = (float*)(smem + 65536) + r * 32 + q * 4;
    dp[0] = bf2f((ushort)(v.x & 0xffff));
    dp[1] = bf2f((ushort)(v.x >> 16));
    dp[2] = bf2f((ushort)(v.y & 0xffff));
    dp[3] = bf2f((ushort)(v.y >> 16));
  }
  // issue W_out k-step 0
  stageB512(wout, smem + 32768, 0, lane, wid);

  // ---- scan setup (n-split)
  const int d = tid >> 1;
  const int s = tid & 1;
  float Aa2h[8];
  {
    float4 v0 = *(const float4*)(A_log + d * NST + 8 * s);
    float4 v1 = *(const float4*)(A_log + d * NST + 8 * s + 4);
    Aa2h[0] = -LOG2E * __expf(v0.x);
    Aa2h[1] = -LOG2E * __expf(v0.y);
    Aa2h[2] = -LOG2E * __expf(v0.z);
    Aa2h[3] = -LOG2E * __expf(v0.w);
    Aa2h[4] = -LOG2E * __expf(v1.x);
    Aa2h[5] = -LOG2E * __expf(v1.y);
    Aa2h[6] = -LOG2E * __expf(v1.z);
    Aa2h[7] = -LOG2E * __expf(v1.w);
  }
  const float Aa2_0 = -LOG2E * __expf(A_log[d * NST]);
  bool pm = true;
#pragma unroll
  for (int k = 0; k < 8; ++k)
    pm = pm && (fabsf(Aa2h[k] - (float)(8 * s + k + 1) * Aa2_0) <=
                1e-3f * fabsf(Aa2h[k]));
  f32x2 h2[4];
  const size_t hb =
      (((size_t)(b * NCHB + c)) * DMODEL + d) * NST + 8 * s;
  {
    float4 v0 = *(const float4*)(hin + hb);
    float4 v1 = *(const float4*)(hin + hb + 4);
    h2[0] = f32x2{v0.x, v0.y};
    h2[1] = f32x2{v0.z, v0.w};
    h2[2] = f32x2{v1.x, v1.y};
    h2[3] = f32x2{v1.z, v1.w};
  }
  const float dsk = Dskip[d];
  __syncthreads();  // BC tile ready

  // ---- scan, y_pre -> LDS (s=0 lane finishes + writes)
  const size_t base = row0 * DMODEL + d;
  const int ywoff = (d & 7) * 2;
  const int ywchunk = d >> 3;
  uint dur[4];
  ushort zr[4];
#pragma unroll
  for (int j = 0; j < 4; ++j) {
    dur[j] = dug[base + (size_t)j * DMODEL];
    if (s == 0) zr[j] = szy[base + (size_t)j * DMODEL];
  }
  for (int lb = 0; lb < LC / 4; ++lb) {
    uint dun[4];
    ushort zn[4];
    if (lb < LC / 4 - 1) {
      size_t nb = base + (size_t)(lb * 4 + 4) * DMODEL;
#pragma unroll
      for (int j = 0; j < 4; ++j) {
        dun[j] = dug[nb + (size_t)j * DMODEL];
        if (s == 0) zn[j] = szy[nb + (size_t)j * DMODEL];
      }
    }
#pragma unroll
    for (int j = 0; j < 4; ++j) {
      int l = lb * 4 + j;
      float dt = h2f((ushort)(dur[j] & 0xffffu));
      float u = bf2f((ushort)(dur[j] >> 16));
      float dtu = dt * u;
      f32x2 dtu2 = {dtu, dtu};
      const float* Bp = (const float*)(smem + 65536) + l * 32 + 8 * s;
      f32x4 B0 = *(const f32x4*)(Bp);
      f32x4 B1 = *(const f32x4*)(Bp + 4);
      f32x4 C0 = *(const f32x4*)(Bp + 16);
      f32x4 C1 = *(const f32x4*)(Bp + 20);
      float y;
      if (pm) {
        f32x2 p[4];
        pow8pk(__builtin_amdgcn_exp2f(dt * Aa2_0), s, p);
        f32x2 y2 = {0.f, 0.f};
        h2[0] = p[0] * h2[0] + dtu2 * B0.xy;
        y2 = y2 + h2[0] * C0.xy;
        h2[1] = p[1] * h2[1] + dtu2 * B0.zw;
        y2 = y2 + h2[1] * C0.zw;
        h2[2] = p[2] * h2[2] + dtu2 * B1.xy;
        y2 = y2 + h2[2] * C1.xy;
        h2[3] = p[3] * h2[3] + dtu2 * B1.zw;
        y2 = y2 + h2[3] * C1.zw;
        y = y2.x + y2.y;
      } else {
        float Bv[8] = {B0.x, B0.y, B0.z, B0.w, B1.x, B1.y, B1.z, B1.w};
        float Cv[8] = {C0.x, C0.y, C0.z, C0.w, C1.x, C1.y, C1.z, C1.w};
        float hs[8] = {h2[0].x, h2[0].y, h2[1].x, h2[1].y,
                       h2[2].x, h2[2].y, h2[3].x, h2[3].y};
        y = 0.f;
#pragma unroll
        for (int k = 0; k < 8; ++k) {
          float ab = __builtin_amdgcn_exp2f(dt * Aa2h[k]);
          hs[k] = fmaf(ab, hs[k], dtu * Bv[k]);
          y = fmaf(hs[k], Cv[k], y);
        }
        h2[0] = f32x2{hs[0], hs[1]};
        h2[1] = f32x2{hs[2], hs[3]};
        h2[2] = f32x2{hs[4], hs[5]};
        h2[3] = f32x2{hs[6], hs[7]};
      }
      y += __shfl_xor(y, 1);  // combine the two n-halves
      if (s == 0) {
        float yp = (y + u * dsk) * bf2f(zr[j]);
        *(ushort*)(smem + l * 512 + ((ywchunk ^ (l & 7)) * 16) + ywoff) =
            (ushort)bf16rne(yp);
      }
    }
#pragma unroll
    for (int j = 0; j < 4; ++j) {
      dur[j] = dun[j];
      if (s == 0) zr[j] = zn[j];
    }
  }
  __syncthreads();  // ypre tile complete

  // ---- output GEMM: wave w -> cols w*32; acc 4x2; dbuf B
  f32x4 acc[4][2];
#pragma unroll
  for (int i = 0; i < 4; ++i)
#pragma unroll
    for (int j = 0; j < 2; ++j) acc[i][j] = {0.f, 0.f, 0.f, 0.f};

  for (int step = 0; step < 8; ++step) {
    char* bufc = smem + 32768 + (step & 1) * 16384;
    if (step < 7)
      stageB512(wout, smem + 32768 + ((step + 1) & 1) * 16384,
                (step + 1) * 32, lane, wid);
    bf16x8 af[4], bfr[2];
#pragma unroll
    for (int i = 0; i < 4; ++i) {
      int r = i * 16 + (lane & 15);
      int sc = step * 4 + (lane >> 4);
      af[i] = *(const bf16x8*)(smem + r * 512 + ((sc ^ (r & 7)) * 16));
    }
#pragma unroll
    for (int j = 0; j < 2; ++j) {
      int r = wid * 32 + j * 16 + (lane & 15);
      int slot = (lane >> 4) ^ ((r + (r >> 2)) & 3);
      bfr[j] = *(const bf16x8*)(bufc + r * 64 + slot * 16);
    }
#pragma unroll
    for (int i = 0; i < 4; ++i)
#pragma unroll
      for (int j = 0; j < 2; ++j)
        acc[i][j] = __builtin_amdgcn_mfma_f32_16x16x32_bf16(af[i], bfr[j],
                                                            acc[i][j], 0, 0, 0);
    __syncthreads();
  }

  const int rbase = (lane >> 4) * 4;
  const int cn = lane & 15;
#pragma unroll
  for (int i = 0; i < 4; ++i)
#pragma unroll
    for (int j = 0; j < 2; ++j) {
      int col = wid * 32 + j * 16 + cn;
      float bs = b_out[col];
#pragma unroll
      for (int r = 0; r < 4; ++r) {
        int row = i * 16 + rbase + r;
        out[(row0 + row) * DMODEL + col] = acc[i][j][r] + bs;
      }
    }
}

// ---------------------------------------------------------------------------
extern "C" void kernel_launch(void* const* d_in, const int* in_sizes, int n_in,
                              void* d_out, int out_size, void* d_ws,
                              size_t ws_size, hipStream_t stream) {
  const float* x       = (const float*)d_in[0];
  const float* A_log   = (const float*)d_in[1];
  const float* D_skip  = (const float*)d_in[2];
  const float* W_B     = (const float*)d_in[3];
  const float* W_C     = (const float*)d_in[4];
  const float* W_delta = (const float*)d_in[5];
  const float* b_delta = (const float*)d_in[6];
  const float* W_in    = (const float*)d_in[7];
  const float* b_in    = (const float*)d_in[8];
  const float* W_out   = (const float*)d_in[9];
  const float* b_out   = (const float*)d_in[10];
  const float* conv_w  = (const float*)d_in[11];
  const float* conv_b  = (const float*)d_in[12];

  const size_t MD = (size_t)MROWS * DMODEL;                // 16.78M
  const size_t HP = (size_t)BATCH * NCHB * DMODEL * NST;   // 4.19M
  ushort* xinb = (ushort*)d_ws;             // x_in bf16 [MD]
  ushort* szy  = xinb + MD;                 // silu(z) bf16 [MD]
  uint* dug    = (uint*)(szy + MD);         // (dt fp16 | u bf16) [MD]
  ushort* bcb  = (ushort*)(dug + MD);       // bc bf16 [MROWS*32]
  float* hst   = (float*)(bcb + (size_t)MROWS * 32);  // h_out -> h_in [HP]
  float* cumA  = hst + HP;                  // [HP]
  ushort* wbf  = (ushort*)(cumA + HP);      // bf16 weights, 270336

  cvt_weights<<<dim3(132), 256, 0, stream>>>(W_in, W_delta, W_out, W_B, W_C, wbf);
  gemm_in<<<dim3(2, MROWS / 64), 256, 0, stream>>>(x, wbf, b_in, xinb, szy);
  fused_mid<<<dim3(BATCH * NCHB), 512, 0, stream>>>(
      xinb, wbf + 131072, wbf + 262144, b_delta, A_log, conv_w, conv_b,
      dug, bcb, hst, cumA);
  scan_combine<<<dim3(BATCH * DMODEL * NST / 256), 256, 0, stream>>>(hst, cumA);
  fused_out<<<dim3(BATCH * NCHB), 512, 0, stream>>>(
      dug, szy, bcb, A_log, hst, D_skip, wbf + 196608, b_out,
      (float*)d_out);
}

// Round 20
// 196.628 us; speedup vs baseline: 1.0144x; 1.0144x over previous
//
#include <hip/hip_runtime.h>
#include <hip/hip_bf16.h>
#include <math.h>

#define BATCH 16
#define LSEQ 4096
#define DMODEL 256
#define NST 16
#define LC 64                   // rows per fused block / scan chunk
#define NCHB (LSEQ / LC)        // 64 chunks per batch
#define MROWS (BATCH * LSEQ)    // 65536
#define LOG2E 1.44269504088896340736f
#define LN2 0.6931471805599453f

typedef float f32x4 __attribute__((ext_vector_type(4)));
typedef float f32x2 __attribute__((ext_vector_type(2)));
typedef short bf16x8 __attribute__((ext_vector_type(8)));

__device__ __forceinline__ float silu_fast(float v) {
  return v * __builtin_amdgcn_rcpf(1.f + __builtin_amdgcn_exp2f(-v * LOG2E));
}
__device__ __forceinline__ float softplus_fast(float v) {
  float l = LN2 * __builtin_amdgcn_logf(1.f + __builtin_amdgcn_exp2f(v * LOG2E));
  return v > 16.f ? v : l;
}
__device__ __forceinline__ uint bf16rne(float f) {
  uint u = __float_as_uint(f);
  return (u + 0x7fffu + ((u >> 16) & 1u)) >> 16;
}
__device__ __forceinline__ float bf2f(ushort u) {
  return __uint_as_float((uint)u << 16);
}
__device__ __forceinline__ ushort f2h(float v) {
  _Float16 h = (_Float16)v;
  return __builtin_bit_cast(ushort, h);
}
__device__ __forceinline__ float h2f(ushort u) {
  return (float)__builtin_bit_cast(_Float16, u);
}
__device__ __forceinline__ uint pk2(float x, float y) {
  return bf16rne(x) | (bf16rne(y) << 16);
}
__device__ __forceinline__ uint4 pk8(float4 a, float4 b) {
  uint4 r;
  r.x = pk2(a.x, a.y);
  r.y = pk2(a.z, a.w);
  r.z = pk2(b.x, b.y);
  r.w = pk2(b.z, b.w);
  return r;
}
// unpack 8 bf16 (uint4) -> 8 floats
__device__ __forceinline__ void ub8(uint4 v, float* o) {
  o[0] = bf2f((ushort)(v.x & 0xffff));
  o[1] = bf2f((ushort)(v.x >> 16));
  o[2] = bf2f((ushort)(v.y & 0xffff));
  o[3] = bf2f((ushort)(v.y >> 16));
  o[4] = bf2f((ushort)(v.z & 0xffff));
  o[5] = bf2f((ushort)(v.z >> 16));
  o[6] = bf2f((ushort)(v.w & 0xffff));
  o[7] = bf2f((ushort)(v.w >> 16));
}

// packed powers: p01={e1,e2} .. p67={e7,e8}, scaled by (s ? e8 : 1).
// Bit-identical pairings to the scalar tree.
__device__ __forceinline__ void pow8pk(float e1, int s, f32x2* p) {
  float e2 = e1 * e1;
  p[0] = f32x2{e1, e2};
  f32x2 e2v = {e2, e2};
  p[1] = p[0] * e2v;                 // {e3, e4}
  f32x2 e4v = {p[1].y, p[1].y};
  p[2] = p[0] * e4v;                 // {e5, e6}
  p[3] = p[1] * e4v;                 // {e7, e8}
  float sel = s ? p[3].y : 1.0f;
  f32x2 selv = {sel, sel};
  p[0] *= selv;
  p[1] *= selv;
  p[2] *= selv;
  p[3] *= selv;
}

// async global(bf16)->LDS, 16 B per lane
__device__ __forceinline__ void glds16(const ushort* g, char* l) {
  __builtin_amdgcn_global_load_lds(
      (const __attribute__((address_space(1))) void*)g,
      (__attribute__((address_space(3))) void*)l, 16, 0, 0);
}

// stage a 256x32 bf16 B k-slice (swizzled layout r*64 + slot*16,
// slot = chunk ^ ((r+(r>>2))&3)); 512 thr: wave w covers 1KB blocks 2w,2w+1.
__device__ __forceinline__ void stageB512(const ushort* gbase, char* dst,
                                          int k0, int lane, int wid) {
#pragma unroll
  for (int c = 0; c < 2; ++c) {
    int r = (wid * 2 + c) * 16 + (lane >> 2);
    int sA = (r + (r >> 2)) & 3;
    int cA = (lane & 3) ^ sA;
    glds16(gbase + (size_t)r * 256 + cA * 8 + k0, dst + (wid * 2 + c) * 1024);
  }
}

// ---------------------------------------------------------------------------
// Weight fp32->bf16 convert (layout unchanged).
// ---------------------------------------------------------------------------
__global__ __launch_bounds__(256) void cvt_weights(
    const float* __restrict__ Win, const float* __restrict__ Wd,
    const float* __restrict__ Wo, const float* __restrict__ WB,
    const float* __restrict__ WC, ushort* __restrict__ dst) {
  size_t i = ((size_t)blockIdx.x * 256 + threadIdx.x) * 8;
  if (i >= 270336) return;
  const float* s;
  size_t o;
  if (i < 131072)      { s = Win; o = i; }
  else if (i < 196608) { s = Wd;  o = i - 131072; }
  else if (i < 262144) { s = Wo;  o = i - 196608; }
  else if (i < 266240) { s = WB;  o = i - 262144; }
  else                 { s = WC;  o = i - 266240; }
  float4 a = *(const float4*)(s + o);
  float4 b = *(const float4*)(s + o + 4);
  *(uint4*)(dst + i) = pk8(a, b);
}

// ---------------------------------------------------------------------------
// gemm_in: xz = x @ W_in^T + b_in. Tile 64x256, grid (2, M/64);
// col<256 -> x_in bf16, col>=256 -> silu(z) bf16.
// ---------------------------------------------------------------------------
__global__ __launch_bounds__(256, 4) void gemm_in(
    const float* __restrict__ A, const ushort* __restrict__ Bbf,
    const float* __restrict__ bias, ushort* __restrict__ out0,
    ushort* __restrict__ out1) {
  constexpr int KD = 256;
  __shared__ char smem[40960];
  const int tid = threadIdx.x;
  const int lane = tid & 63, wid = tid >> 6;
  const int M0 = blockIdx.y * 64;
  const int N0 = blockIdx.x * 256;

  const int rA = tid >> 2, cA = tid & 3;
  const int sA = (rA + (rA >> 2)) & 3;
  const int ldsAoff = rA * 64 + ((cA ^ sA) * 16);
  const float* gA32 = A + (size_t)(M0 + rA) * KD + cA * 8;
  const ushort* gB = Bbf + (size_t)(N0 + rA) * KD + ((cA ^ sA) * 8);

  f32x4 acc[4][4];
#pragma unroll
  for (int i = 0; i < 4; ++i)
#pragma unroll
    for (int j = 0; j < 4; ++j) acc[i][j] = {0.f, 0.f, 0.f, 0.f};

  {
#pragma unroll
    for (int i = 0; i < 4; ++i)
      glds16(gB + (size_t)i * 64 * KD, smem + 4096 + i * 4096 + wid * 1024);
    float4 a0 = *(const float4*)(gA32);
    float4 a1 = *(const float4*)(gA32 + 4);
    *(uint4*)(smem + ldsAoff) = pk8(a0, a1);
  }
  __syncthreads();

  for (int step = 0; step < 8; ++step) {
    const int cur = step & 1;
    char* bufc = smem + cur * 20480;
    char* bufn = smem + (cur ^ 1) * 20480;
    float4 na0, na1;
    if (step < 7) {
      const int k0 = (step + 1) * 32;
#pragma unroll
      for (int i = 0; i < 4; ++i)
        glds16(gB + (size_t)i * 64 * KD + k0,
               bufn + 4096 + i * 4096 + wid * 1024);
      na0 = *(const float4*)(gA32 + k0);
      na1 = *(const float4*)(gA32 + k0 + 4);
    }
    bf16x8 af[4], bfr[4];
#pragma unroll
    for (int i = 0; i < 4; ++i) {
      int r = i * 16 + (lane & 15);
      int slot = (lane >> 4) ^ ((r + (r >> 2)) & 3);
      af[i] = *(const bf16x8*)(bufc + r * 64 + slot * 16);
    }
#pragma unroll
    for (int j = 0; j < 4; ++j) {
      int r = wid * 64 + j * 16 + (lane & 15);
      int slot = (lane >> 4) ^ ((r + (r >> 2)) & 3);
      bfr[j] = *(const bf16x8*)(bufc + 4096 + r * 64 + slot * 16);
    }
#pragma unroll
    for (int i = 0; i < 4; ++i)
#pragma unroll
      for (int j = 0; j < 4; ++j)
        acc[i][j] = __builtin_amdgcn_mfma_f32_16x16x32_bf16(af[i], bfr[j],
                                                            acc[i][j], 0, 0, 0);
    if (step < 7) *(uint4*)(bufn + ldsAoff) = pk8(na0, na1);
    __syncthreads();
  }

  const int rbase = (lane >> 4) * 4;
  const int cn = lane & 15;
#pragma unroll
  for (int i = 0; i < 4; ++i) {
#pragma unroll
    for (int j = 0; j < 4; ++j) {
      int col = N0 + wid * 64 + j * 16 + cn;
      float bs = bias[col];
#pragma unroll
      for (int r = 0; r < 4; ++r) {
        int row = M0 + i * 16 + rbase + r;
        float v = acc[i][j][r] + bs;
        if (col < DMODEL)
          out0[(size_t)row * DMODEL + col] = (ushort)bf16rne(v);
        else
          out1[(size_t)row * DMODEL + (col - DMODEL)] =
              (ushort)bf16rne(silu_fast(v));
      }
    }
  }
}

// ---------------------------------------------------------------------------
// K2 fused_mid (512 thr, 72 KB LDS): conv+silu -> xc tile, delta GEMM
// (single-buffered W_delta), BC GEMM (interleaved), scan pass1 n-split
// with packed-f32 inner loop.  (R13/R17 version — best measured)
// ---------------------------------------------------------------------------
__global__ __launch_bounds__(512, 4) void fused_mid(
    const ushort* __restrict__ xin, const ushort* __restrict__ wdl,
    const ushort* __restrict__ wbc, const float* __restrict__ b_delta,
    const float* __restrict__ A_log, const float* __restrict__ conv_w,
    const float* __restrict__ conv_b, ushort* __restrict__ xc_g,
    ushort* __restrict__ dl_g, ushort* __restrict__ bc_g,
    float* __restrict__ hout, float* __restrict__ cumA) {
  __shared__ char smem[73728];
  const int tid = threadIdx.x, lane = tid & 63, wid = tid >> 6;
  const int b = blockIdx.x / NCHB, c = blockIdx.x % NCHB;
  const int l0 = c * LC;
  const size_t row0 = (size_t)b * LSEQ + l0;

  // ---- WBC staging -> @49152
  {
#pragma unroll
    for (int cc = 0; cc < 2; ++cc) {
      int row = (wid * 2 + cc) * 2 + (lane >> 5);
      int cB = (lane & 31) ^ (row & 7);
      glds16(wbc + (size_t)row * 256 + cB * 8,
             smem + 49152 + (wid * 2 + cc) * 1024);
    }
  }
  // ---- W_delta k-step 0 -> @32768
  stageB512(wdl, smem + 32768, 0, lane, wid);

  // ---- conv + silu -> xc tile + global (each thread 4 l-rows x 8 d)
  {
    const int dq = tid & 31;
    const int d0 = dq * 8;
    float w0[8], w1[8], w2[8], cb[8];
#pragma unroll
    for (int k = 0; k < 8; ++k) {
      w0[k] = conv_w[(d0 + k) * 3 + 0];
      w1[k] = conv_w[(d0 + k) * 3 + 1];
      w2[k] = conv_w[(d0 + k) * 3 + 2];
      cb[k] = conv_b[d0 + k];
    }
#pragma unroll
    for (int it = 0; it < 4; ++it) {
      const int lr = it * 16 + (tid >> 5);
      const int l = l0 + lr;
      const size_t bp = (row0 + lr) * DMODEL + d0;
      uint4 zf4 = {0u, 0u, 0u, 0u};
      uint4 um = (l > 0) ? *(const uint4*)(xin + bp - DMODEL) : zf4;
      uint4 uc4 = *(const uint4*)(xin + bp);
      uint4 up = (l < LSEQ - 1) ? *(const uint4*)(xin + bp + DMODEL) : zf4;
      float mv[8], cv[8], pv[8], ov[8];
      ub8(um, mv);
      ub8(uc4, cv);
      ub8(up, pv);
#pragma unroll
      for (int k = 0; k < 8; ++k) {
        float o = fmaf(w0[k], mv[k], fmaf(w1[k], cv[k], fmaf(w2[k], pv[k], cb[k])));
        ov[k] = silu_fast(o);
      }
      uint4 r4;
      r4.x = pk2(ov[0], ov[1]);
      r4.y = pk2(ov[2], ov[3]);
      r4.z = pk2(ov[4], ov[5]);
      r4.w = pk2(ov[6], ov[7]);
      *(uint4*)(xc_g + bp) = r4;
      *(uint4*)(smem + lr * 512 + ((dq ^ (lr & 7)) * 16)) = r4;
    }
  }
  __syncthreads();  // xc tile + WBC + B-k0 ready

  // ---- delta GEMM (single-buf B) with BC GEMM interleaved
  f32x4 acc[4][2];
#pragma unroll
  for (int i = 0; i < 4; ++i)
#pragma unroll
    for (int j = 0; j < 2; ++j) acc[i][j] = {0.f, 0.f, 0.f, 0.f};
  f32x4 accbc = {0.f, 0.f, 0.f, 0.f};

  for (int step = 0; step < 8; ++step) {
    bf16x8 af[4], bfr[2];
#pragma unroll
    for (int i = 0; i < 4; ++i) {
      int r = i * 16 + (lane & 15);
      int sc = step * 4 + (lane >> 4);
      af[i] = *(const bf16x8*)(smem + r * 512 + ((sc ^ (r & 7)) * 16));
    }
#pragma unroll
    for (int j = 0; j < 2; ++j) {
      int r = wid * 32 + j * 16 + (lane & 15);
      int slot = (lane >> 4) ^ ((r + (r >> 2)) & 3);
      bfr[j] = *(const bf16x8*)(smem + 32768 + r * 64 + slot * 16);
    }
#pragma unroll
    for (int i = 0; i < 4; ++i)
#pragma unroll
      for (int j = 0; j < 2; ++j)
        acc[i][j] = __builtin_amdgcn_mfma_f32_16x16x32_bf16(af[i], bfr[j],
                                                            acc[i][j], 0, 0, 0);
    __syncthreads();  // all reads of B buffer done
    if (step < 7) stageB512(wdl, smem + 32768, (step + 1) * 32, lane, wid);
    {  // BC GEMM step
      int sc = step * 4 + (lane >> 4);
      int ra = (wid >> 1) * 16 + (lane & 15);
      bf16x8 a2 = *(const bf16x8*)(smem + ra * 512 + ((sc ^ (ra & 7)) * 16));
      int br = (wid & 1) * 16 + (lane & 15);
      bf16x8 b2 =
          *(const bf16x8*)(smem + 49152 + br * 512 + ((sc ^ (br & 7)) * 16));
      accbc = __builtin_amdgcn_mfma_f32_16x16x32_bf16(a2, b2, accbc, 0, 0, 0);
    }
    __syncthreads();  // staged B visible
  }

  // ---- delta epilogue -> fp16 tile @32768, swz
  const int rbase = (lane >> 4) * 4;
  const int cn = lane & 15;
#pragma unroll
  for (int i = 0; i < 4; ++i)
#pragma unroll
    for (int j = 0; j < 2; ++j) {
      int col = wid * 32 + j * 16 + cn;
      float bs = b_delta[col];
#pragma unroll
      for (int r = 0; r < 4; ++r) {
        int row = i * 16 + rbase + r;
        *(ushort*)(smem + 32768 + row * 512 +
                   ((col * 2) ^ (((row >> 2) & 3) << 5))) =
            f2h(softplus_fast(acc[i][j][r] + bs));
      }
    }
  // ---- BC epilogue
  {
#pragma unroll
    for (int r = 0; r < 4; ++r) {
      int row = (wid >> 1) * 16 + rbase + r;
      int col = (wid & 1) * 16 + cn;
      ushort bv = (ushort)bf16rne(accbc[r]);
      ((float*)(smem + 65536))[row * 32 + col] = bf2f(bv);
      bc_g[(row0 + row) * 32 + col] = bv;
    }
  }
  __syncthreads();

  // ---- dl_g coalesced write
#pragma unroll
  for (int it = 0; it < 4; ++it) {
    int idx = it * 512 + tid;
    int row = idx >> 5, ch = idx & 31;
    *(uint4*)(dl_g + (row0 + row) * DMODEL + ch * 8) =
        *(const uint4*)(smem + 32768 + row * 512 +
                        ((ch ^ (((row >> 2) & 3) << 1)) * 16));
  }

  // ---- scan pass1, n-split, packed f32
  const int d = tid >> 1;
  const int s = tid & 1;
  float Aa2h[8];
  {
    float4 v0 = *(const float4*)(A_log + d * NST + 8 * s);
    float4 v1 = *(const float4*)(A_log + d * NST + 8 * s + 4);
    Aa2h[0] = -LOG2E * __expf(v0.x);
    Aa2h[1] = -LOG2E * __expf(v0.y);
    Aa2h[2] = -LOG2E * __expf(v0.z);
    Aa2h[3] = -LOG2E * __expf(v0.w);
    Aa2h[4] = -LOG2E * __expf(v1.x);
    Aa2h[5] = -LOG2E * __expf(v1.y);
    Aa2h[6] = -LOG2E * __expf(v1.z);
    Aa2h[7] = -LOG2E * __expf(v1.w);
  }
  const float Aa2_0 = -LOG2E * __expf(A_log[d * NST]);
  bool pm = true;
#pragma unroll
  for (int k = 0; k < 8; ++k)
    pm = pm && (fabsf(Aa2h[k] - (float)(8 * s + k + 1) * Aa2_0) <=
                1e-3f * fabsf(Aa2h[k]));

  float sdt = 0.f;
  const int uoff0 = (d & 7) * 2;
  const int uchunk = d >> 3;
  if (pm) {
    f32x2 h2[4];
#pragma unroll
    for (int q = 0; q < 4; ++q) h2[q] = f32x2{0.f, 0.f};
#pragma unroll 4
    for (int l = 0; l < LC; ++l) {
      float dt = h2f(*(const ushort*)(smem + 32768 + l * 512 +
                                      ((d * 2) ^ (((l >> 2) & 3) << 5))));
      float u = bf2f(*(const ushort*)(smem + l * 512 +
                                      ((uchunk ^ (l & 7)) * 16) + uoff0));
      sdt += dt;
      float dtu = dt * u;
      f32x2 dtu2 = {dtu, dtu};
      const float* Bp = (const float*)(smem + 65536) + l * 32 + 8 * s;
      f32x4 B0 = *(const f32x4*)(Bp);
      f32x4 B1 = *(const f32x4*)(Bp + 4);
      f32x2 p[4];
      pow8pk(__builtin_amdgcn_exp2f(dt * Aa2_0), s, p);
      h2[0] = p[0] * h2[0] + dtu2 * B0.xy;
      h2[1] = p[1] * h2[1] + dtu2 * B0.zw;
      h2[2] = p[2] * h2[2] + dtu2 * B1.xy;
      h2[3] = p[3] * h2[3] + dtu2 * B1.zw;
    }
    f32x2 cum[4];
    pow8pk(__builtin_amdgcn_exp2f(sdt * Aa2_0), s, cum);
    const size_t ob =
        (((size_t)(b * NCHB + c)) * DMODEL + d) * NST + 8 * s;
    float4 hv0 = {h2[0].x, h2[0].y, h2[1].x, h2[1].y};
    float4 hv1 = {h2[2].x, h2[2].y, h2[3].x, h2[3].y};
    *(float4*)(hout + ob) = hv0;
    *(float4*)(hout + ob + 4) = hv1;
    float4 cv0 = {cum[0].x, cum[0].y, cum[1].x, cum[1].y};
    float4 cv1 = {cum[2].x, cum[2].y, cum[3].x, cum[3].y};
    *(float4*)(cumA + ob) = cv0;
    *(float4*)(cumA + ob + 4) = cv1;
  } else {
    float h[8];
#pragma unroll
    for (int k = 0; k < 8; ++k) h[k] = 0.f;
#pragma unroll 4
    for (int l = 0; l < LC; ++l) {
      float dt = h2f(*(const ushort*)(smem + 32768 + l * 512 +
                                      ((d * 2) ^ (((l >> 2) & 3) << 5))));
      float u = bf2f(*(const ushort*)(smem + l * 512 +
                                      ((uchunk ^ (l & 7)) * 16) + uoff0));
      sdt += dt;
      float dtu = dt * u;
      const float* Bp = (const float*)(smem + 65536) + l * 32 + 8 * s;
      f32x4 B0 = *(const f32x4*)(Bp);
      f32x4 B1 = *(const f32x4*)(Bp + 4);
      float Bv[8] = {B0.x, B0.y, B0.z, B0.w, B1.x, B1.y, B1.z, B1.w};
#pragma unroll
      for (int k = 0; k < 8; ++k) {
        float ab = __builtin_amdgcn_exp2f(dt * Aa2h[k]);
        h[k] = fmaf(ab, h[k], dtu * Bv[k]);
      }
    }
    const size_t ob =
        (((size_t)(b * NCHB + c)) * DMODEL + d) * NST + 8 * s;
#pragma unroll
    for (int q = 0; q < 2; ++q) {
      float4 hv = {h[q * 4 + 0], h[q * 4 + 1], h[q * 4 + 2], h[q * 4 + 3]};
      *(float4*)(hout + ob + q * 4) = hv;
      float4 cvv = {__builtin_amdgcn_exp2f(sdt * Aa2h[q * 4 + 0]),
                    __builtin_amdgcn_exp2f(sdt * Aa2h[q * 4 + 1]),
                    __builtin_amdgcn_exp2f(sdt * Aa2h[q * 4 + 2]),
                    __builtin_amdgcn_exp2f(sdt * Aa2h[q * 4 + 3])};
      *(float4*)(cumA + ob + q * 4) = cvv;
    }
  }
}

// ---------------------------------------------------------------------------
// Scan combine over 64 chunks; in-place h_out -> h_in.
// ---------------------------------------------------------------------------
__global__ __launch_bounds__(256) void scan_combine(
    float* __restrict__ hstate, const float* __restrict__ cumA) {
  const int t = blockIdx.x * 256 + threadIdx.x;
  const int n = t & (NST - 1);
  const int dd = (t / NST) & (DMODEL - 1);
  const int b = t / (NST * DMODEL);
  float h = 0.f;
  for (int c = 0; c < NCHB; ++c) {
    size_t idx = (((size_t)(b * NCHB + c)) * DMODEL + dd) * NST + n;
    float ho = hstate[idx];
    float ca = cumA[idx];
    hstate[idx] = h;
    h = fmaf(ca, h, ho);
  }
}

// ---------------------------------------------------------------------------
// K3 fused_out (512 thr, 72 KB LDS): scan pass3 (n-split x2, packed f32;
// s=0 lane owns z + yp + LDS write) -> y_pre tile -> GEMM W_out (dbuf)
// -> d_out.  (R13/R17 version — best measured)
// ---------------------------------------------------------------------------
__global__ __launch_bounds__(512, 4) void fused_out(
    const ushort* __restrict__ dl, const ushort* __restrict__ xcb,
    const ushort* __restrict__ szy, const ushort* __restrict__ bcb,
    const float* __restrict__ A_log, const float* __restrict__ hin,
    const float* __restrict__ Dskip, const ushort* __restrict__ wout,
    const float* __restrict__ b_out, float* __restrict__ out) {
  __shared__ char smem[73728];
  const int tid = threadIdx.x, lane = tid & 63, wid = tid >> 6;
  const int b = blockIdx.x / NCHB, c = blockIdx.x % NCHB;
  const int l0 = c * LC;
  const size_t row0 = (size_t)b * LSEQ + l0;

  // stage BC f32 tile
  {
    int r = tid >> 3, q = tid & 7;
    uint2 v = *(const uint2*)(bcb + (row0 + r) * 32 + q * 4);
    float* dp = (float*)(smem + 65536) + r * 32 + q * 4;
    dp[0] = bf2f((ushort)(v.x & 0xffff));
    dp[1] = bf2f((ushort)(v.x >> 16));
    dp[2] = bf2f((ushort)(v.y & 0xffff));
    dp[3] = bf2f((ushort)(v.y >> 16));
  }
  // issue W_out k-step 0
  stageB512(wout, smem + 32768, 0, lane, wid);

  // ---- scan setup (n-split)
  const int d = tid >> 1;
  const int s = tid & 1;
  float Aa2h[8];
  {
    float4 v0 = *(const float4*)(A_log + d * NST + 8 * s);
    float4 v1 = *(const float4*)(A_log + d * NST + 8 * s + 4);
    Aa2h[0] = -LOG2E * __expf(v0.x);
    Aa2h[1] = -LOG2E * __expf(v0.y);
    Aa2h[2] = -LOG2E * __expf(v0.z);
    Aa2h[3] = -LOG2E * __expf(v0.w);
    Aa2h[4] = -LOG2E * __expf(v1.x);
    Aa2h[5] = -LOG2E * __expf(v1.y);
    Aa2h[6] = -LOG2E * __expf(v1.z);
    Aa2h[7] = -LOG2E * __expf(v1.w);
  }
  const float Aa2_0 = -LOG2E * __expf(A_log[d * NST]);
  bool pm = true;
#pragma unroll
  for (int k = 0; k < 8; ++k)
    pm = pm && (fabsf(Aa2h[k] - (float)(8 * s + k + 1) * Aa2_0) <=
                1e-3f * fabsf(Aa2h[k]));
  f32x2 h2[4];
  const size_t hb =
      (((size_t)(b * NCHB + c)) * DMODEL + d) * NST + 8 * s;
  {
    float4 v0 = *(const float4*)(hin + hb);
    float4 v1 = *(const float4*)(hin + hb + 4);
    h2[0] = f32x2{v0.x, v0.y};
    h2[1] = f32x2{v0.z, v0.w};
    h2[2] = f32x2{v1.x, v1.y};
    h2[3] = f32x2{v1.z, v1.w};
  }
  const float dsk = Dskip[d];
  __syncthreads();  // BC tile ready

  // ---- scan, y_pre -> LDS (s=0 lane finishes + writes)
  const size_t base = row0 * DMODEL + d;
  const int ywoff = (d & 7) * 2;
  const int ywchunk = d >> 3;
  ushort dtr[4], ur[4], zr[4];
#pragma unroll
  for (int j = 0; j < 4; ++j) {
    dtr[j] = dl[base + (size_t)j * DMODEL];
    ur[j] = xcb[base + (size_t)j * DMODEL];
    if (s == 0) zr[j] = szy[base + (size_t)j * DMODEL];
  }
  for (int lb = 0; lb < LC / 4; ++lb) {
    ushort dtn[4], un[4], zn[4];
    if (lb < LC / 4 - 1) {
      size_t nb = base + (size_t)(lb * 4 + 4) * DMODEL;
#pragma unroll
      for (int j = 0; j < 4; ++j) {
        dtn[j] = dl[nb + (size_t)j * DMODEL];
        un[j] = xcb[nb + (size_t)j * DMODEL];
        if (s == 0) zn[j] = szy[nb + (size_t)j * DMODEL];
      }
    }
#pragma unroll
    for (int j = 0; j < 4; ++j) {
      int l = lb * 4 + j;
      float dt = h2f(dtr[j]);
      float u = bf2f(ur[j]);
      float dtu = dt * u;
      f32x2 dtu2 = {dtu, dtu};
      const float* Bp = (const float*)(smem + 65536) + l * 32 + 8 * s;
      f32x4 B0 = *(const f32x4*)(Bp);
      f32x4 B1 = *(const f32x4*)(Bp + 4);
      f32x4 C0 = *(const f32x4*)(Bp + 16);
      f32x4 C1 = *(const f32x4*)(Bp + 20);
      float y;
      if (pm) {
        f32x2 p[4];
        pow8pk(__builtin_amdgcn_exp2f(dt * Aa2_0), s, p);
        f32x2 y2 = {0.f, 0.f};
        h2[0] = p[0] * h2[0] + dtu2 * B0.xy;
        y2 = y2 + h2[0] * C0.xy;
        h2[1] = p[1] * h2[1] + dtu2 * B0.zw;
        y2 = y2 + h2[1] * C0.zw;
        h2[2] = p[2] * h2[2] + dtu2 * B1.xy;
        y2 = y2 + h2[2] * C1.xy;
        h2[3] = p[3] * h2[3] + dtu2 * B1.zw;
        y2 = y2 + h2[3] * C1.zw;
        y = y2.x + y2.y;
      } else {
        float Bv[8] = {B0.x, B0.y, B0.z, B0.w, B1.x, B1.y, B1.z, B1.w};
        float Cv[8] = {C0.x, C0.y, C0.z, C0.w, C1.x, C1.y, C1.z, C1.w};
        float hs[8] = {h2[0].x, h2[0].y, h2[1].x, h2[1].y,
                       h2[2].x, h2[2].y, h2[3].x, h2[3].y};
        y = 0.f;
#pragma unroll
        for (int k = 0; k < 8; ++k) {
          float ab = __builtin_amdgcn_exp2f(dt * Aa2h[k]);
          hs[k] = fmaf(ab, hs[k], dtu * Bv[k]);
          y = fmaf(hs[k], Cv[k], y);
        }
        h2[0] = f32x2{hs[0], hs[1]};
        h2[1] = f32x2{hs[2], hs[3]};
        h2[2] = f32x2{hs[4], hs[5]};
        h2[3] = f32x2{hs[6], hs[7]};
      }
      y += __shfl_xor(y, 1);  // combine the two n-halves
      if (s == 0) {
        float yp = (y + u * dsk) * bf2f(zr[j]);
        *(ushort*)(smem + l * 512 + ((ywchunk ^ (l & 7)) * 16) + ywoff) =
            (ushort)bf16rne(yp);
      }
    }
#pragma unroll
    for (int j = 0; j < 4; ++j) {
      dtr[j] = dtn[j];
      ur[j] = un[j];
      if (s == 0) zr[j] = zn[j];
    }
  }
  __syncthreads();  // ypre tile complete

  // ---- output GEMM: wave w -> cols w*32; acc 4x2; dbuf B
  f32x4 acc[4][2];
#pragma unroll
  for (int i = 0; i < 4; ++i)
#pragma unroll
    for (int j = 0; j < 2; ++j) acc[i][j] = {0.f, 0.f, 0.f, 0.f};

  for (int step = 0; step < 8; ++step) {
    char* bufc = smem + 32768 + (step & 1) * 16384;
    if (step < 7)
      stageB512(wout, smem + 32768 + ((step + 1) & 1) * 16384,
                (step + 1) * 32, lane, wid);
    bf16x8 af[4], bfr[2];
#pragma unroll
    for (int i = 0; i < 4; ++i) {
      int r = i * 16 + (lane & 15);
      int sc = step * 4 + (lane >> 4);
      af[i] = *(const bf16x8*)(smem + r * 512 + ((sc ^ (r & 7)) * 16));
    }
#pragma unroll
    for (int j = 0; j < 2; ++j) {
      int r = wid * 32 + j * 16 + (lane & 15);
      int slot = (lane >> 4) ^ ((r + (r >> 2)) & 3);
      bfr[j] = *(const bf16x8*)(bufc + r * 64 + slot * 16);
    }
#pragma unroll
    for (int i = 0; i < 4; ++i)
#pragma unroll
      for (int j = 0; j < 2; ++j)
        acc[i][j] = __builtin_amdgcn_mfma_f32_16x16x32_bf16(af[i], bfr[j],
                                                            acc[i][j], 0, 0, 0);
    __syncthreads();
  }

  const int rbase = (lane >> 4) * 4;
  const int cn = lane & 15;
#pragma unroll
  for (int i = 0; i < 4; ++i)
#pragma unroll
    for (int j = 0; j < 2; ++j) {
      int col = wid * 32 + j * 16 + cn;
      float bs = b_out[col];
#pragma unroll
      for (int r = 0; r < 4; ++r) {
        int row = i * 16 + rbase + r;
        out[(row0 + row) * DMODEL + col] = acc[i][j][r] + bs;
      }
    }
}

// ---------------------------------------------------------------------------
extern "C" void kernel_launch(void* const* d_in, const int* in_sizes, int n_in,
                              void* d_out, int out_size, void* d_ws,
                              size_t ws_size, hipStream_t stream) {
  const float* x       = (const float*)d_in[0];
  const float* A_log   = (const float*)d_in[1];
  const float* D_skip  = (const float*)d_in[2];
  const float* W_B     = (const float*)d_in[3];
  const float* W_C     = (const float*)d_in[4];
  const float* W_delta = (const float*)d_in[5];
  const float* b_delta = (const float*)d_in[6];
  const float* W_in    = (const float*)d_in[7];
  const float* b_in    = (const float*)d_in[8];
  const float* W_out   = (const float*)d_in[9];
  const float* b_out   = (const float*)d_in[10];
  const float* conv_w  = (const float*)d_in[11];
  const float* conv_b  = (const float*)d_in[12];

  const size_t MD = (size_t)MROWS * DMODEL;                // 16.78M
  const size_t HP = (size_t)BATCH * NCHB * DMODEL * NST;   // 4.19M
  ushort* xinb = (ushort*)d_ws;             // x_in bf16 [MD]
  ushort* dl   = xinb + MD;                 // delta fp16 [MD]
  ushort* szy  = dl + MD;                   // silu(z) bf16 [MD]
  ushort* xcb  = szy + MD;                  // xc bf16 [MD]
  ushort* bcb  = xcb + MD;                  // bc bf16 [MROWS*32]
  float* hst   = (float*)(bcb + (size_t)MROWS * 32);  // h_out -> h_in [HP]
  float* cumA  = hst + HP;                  // [HP]
  ushort* wbf  = (ushort*)(cumA + HP);      // bf16 weights, 270336

  cvt_weights<<<dim3(132), 256, 0, stream>>>(W_in, W_delta, W_out, W_B, W_C, wbf);
  gemm_in<<<dim3(2, MROWS / 64), 256, 0, stream>>>(x, wbf, b_in, xinb, szy);
  fused_mid<<<dim3(BATCH * NCHB), 512, 0, stream>>>(
      xinb, wbf + 131072, wbf + 262144, b_delta, A_log, conv_w, conv_b,
      xcb, dl, bcb, hst, cumA);
  scan_combine<<<dim3(BATCH * DMODEL * NST / 256), 256, 0, stream>>>(hst, cumA);
  fused_out<<<dim3(BATCH * NCHB), 512, 0, stream>>>(
      dl, xcb, szy, bcb, A_log, hst, D_skip, wbf + 196608, b_out,
      (float*)d_out);
}